// Round 3
// baseline (924.903 us; speedup 1.0000x reference)
//
#include <hip/hip_runtime.h>
#include <hip/hip_bf16.h>
#include <stdint.h>

// Problem constants (fixed by setup_inputs)
#define T_TOK 4096   // B*S tokens
#define D_DIM 1024
#define F_DIM 4096
#define E_NUM 8
#define MAXTOK 4096  // worst-case tokens per expert
#define TOTROW 8192  // total gathered rows = 2*T_TOK

typedef __attribute__((ext_vector_type(8))) short short8;
typedef __attribute__((ext_vector_type(4))) float floatx4;

__device__ __forceinline__ unsigned short f2bf(float f) {
    union { float f; unsigned u; } v; v.f = f;
    unsigned u = v.u;
    u += 0x7fff + ((u >> 16) & 1);   // round-to-nearest-even
    return (unsigned short)(u >> 16);
}

// async global -> LDS, 16B per lane. LDS dest must be wave-uniform base; HW adds lane*16.
__device__ __forceinline__ void async_copy16(const unsigned short* g, unsigned short* l) {
    __builtin_amdgcn_global_load_lds(
        (__attribute__((address_space(1))) void*)(g),
        (__attribute__((address_space(3))) void*)(l), 16, 0, 0);
}

// ---------------- fp32 -> bf16 bulk convert (grid-stride, 8 elems/thread) ----------------
__global__ __launch_bounds__(256) void cvt_kernel(
    const float* __restrict__ src, unsigned short* __restrict__ dst, int n8)
{
    int i = blockIdx.x * blockDim.x + threadIdx.x;
    int stride = gridDim.x * blockDim.x;
    for (; i < n8; i += stride) {
        const float4* s = (const float4*)src + 2 * (size_t)i;
        float4 a = s[0], b = s[1];
        short8 o;
        o[0] = (short)f2bf(a.x); o[1] = (short)f2bf(a.y);
        o[2] = (short)f2bf(a.z); o[3] = (short)f2bf(a.w);
        o[4] = (short)f2bf(b.x); o[5] = (short)f2bf(b.y);
        o[6] = (short)f2bf(b.z); o[7] = (short)f2bf(b.w);
        *((short8*)dst + (size_t)i) = o;
    }
}

// ---------------- router: logits -> top2 -> scatter ----------------
__global__ __launch_bounds__(64) void router_kernel(
    const float* __restrict__ x, const float* __restrict__ gw,
    int* __restrict__ counts, int* __restrict__ tok, float* __restrict__ rw,
    int* __restrict__ se, int* __restrict__ sp, float* __restrict__ sw)
{
    const int t = blockIdx.x;
    const int l = threadIdx.x;
    const float* xr = x + (size_t)t * D_DIM;
    float acc[E_NUM];
#pragma unroll
    for (int e = 0; e < E_NUM; e++) acc[e] = 0.f;
    for (int d = l; d < D_DIM; d += 64) {
        float xv = xr[d];
#pragma unroll
        for (int e = 0; e < E_NUM; e++) acc[e] += xv * gw[e * D_DIM + d];
    }
#pragma unroll
    for (int e = 0; e < E_NUM; e++) {
        float a = acc[e];
        for (int off = 32; off > 0; off >>= 1) a += __shfl_xor(a, off, 64);
        acc[e] = a;
    }
    if (l == 0) {
        int e0 = 0;
#pragma unroll
        for (int e = 1; e < E_NUM; e++) if (acc[e] > acc[e0]) e0 = e;
        int e1 = (e0 == 0) ? 1 : 0;
#pragma unroll
        for (int e = 0; e < E_NUM; e++) if (e != e0 && acc[e] > acc[e1]) e1 = e;
        float w0 = 1.f / (1.f + expf(acc[e1] - acc[e0]));   // renorm top-2; denom cancels
        float w1 = 1.f - w0;
        int p0 = atomicAdd(&counts[e0], 1);
        tok[e0 * MAXTOK + p0] = t; rw[e0 * MAXTOK + p0] = w0;
        int p1 = atomicAdd(&counts[e1], 1);
        tok[e1 * MAXTOK + p1] = t; rw[e1 * MAXTOK + p1] = w1;
        se[2 * t] = e0; sp[2 * t] = p0; sw[2 * t] = w0;
        se[2 * t + 1] = e1; sp[2 * t + 1] = p1; sw[2 * t + 1] = w1;
    }
}

__global__ void prefix_kernel(const int* __restrict__ counts, int* __restrict__ offsets)
{
    if (threadIdx.x == 0 && blockIdx.x == 0) {
        int run = 0;
        for (int e = 0; e < E_NUM; e++) { offsets[e] = run; run += counts[e]; }
    }
}

// ================= FAST PATH: counted-vmcnt pipelined bf16 GEMMs =================
//
// R3: replace the 2-phase {prefetch; compute; __syncthreads=vmcnt(0) drain} loop with
// the m201-style counted-vmcnt pipeline:
//   3 LDS buffers, prefetch distance 2, ONE raw s_barrier per K-step preceded by
//   s_waitcnt vmcnt(4) (= one tile's 4 loads/wave stay in flight). Tile k+2's loads
//   are issued at iter k and waited at iter k+2 -> ~1.5 iterations of latency hiding,
//   and the loop never drains vmcnt to 0.
// Correctness: per-wave counted wait before barrier => all waves' tile-k LDS writes
// visible after barrier; buffer (k+2)%3 was last ds_read at iter k-1, sealed by the
// iter-k barrier (each wave's ds_reads complete before its barrier because their MFMA
// consumers force lgkmcnt waits). "memory" clobber pins compiler ordering.
// R2's T2 chunk-XOR swizzle retained (bank conflicts measured 0).

#define NT1 (D_DIM / 32)   // 32 K-tiles
#define NT2 (F_DIM / 32)   // 128 K-tiles

// gemm1f: h = silu(x@w1^T) * (x@w3^T), gathered bf16 rows, 128x64 tile
__global__ __launch_bounds__(256, 3) void gemm1f_kernel(
    const unsigned short* __restrict__ xb,
    const unsigned short* __restrict__ w1b, const unsigned short* __restrict__ w3b,
    const int* __restrict__ counts, const int* __restrict__ offsets,
    const int* __restrict__ tok, unsigned short* __restrict__ h)
{
    // grid = (32, 64, 8) = 16384 blocks; XCD k == expert k, tm fastest
    const int lin = blockIdx.x + 32 * (blockIdx.y + 64 * blockIdx.z);
    const int w = (lin & 7) * 2048 + (lin >> 3);
    const int tm = w & 31;
    const int tn = (w >> 5) & 63;
    const int e  = w >> 11;

    const int cnt = counts[e];
    if (tm * 128 >= cnt) return;          // uniform early exit
    const int tid = threadIdx.x;

    __shared__ unsigned short sA[3 * 128 * 32];   // 24KB
    __shared__ unsigned short sB1[3 * 64 * 32];   // 12KB
    __shared__ unsigned short sB3[3 * 64 * 32];   // 12KB
    __shared__ int tokS[128];

    if (tid < 128) {
        int r = tm * 128 + tid;
        tokS[tid] = tok[e * MAXTOK + (r < cnt ? r : cnt - 1)];  // clamp; masked at store
    }
    __syncthreads();

    const int wave = tid >> 6, lane = tid & 63;
    const int wx = wave & 1, wy = wave >> 1;
    const int quad = lane >> 4, tl = lane & 15;

    // staging: row = tid>>2 (0..63), dest chunk = tid&3; SOURCE chunk is swizzled (T2)
    const int sr = tid >> 2;
    const int scw = ((tid & 3) ^ ((sr >> 1) & 3)) * 8;
    const unsigned short* gA0 = xb + (size_t)tokS[sr] * D_DIM + scw;
    const unsigned short* gA1 = xb + (size_t)tokS[sr + 64] * D_DIM + scw;
    const size_t wrow = (size_t)e * F_DIM + (size_t)tn * 64 + sr;
    const unsigned short* gB1 = w1b + wrow * D_DIM + scw;
    const unsigned short* gB3 = w3b + wrow * D_DIM + scw;

    const int l0 = wave * 512;          // A buffer half 0
    const int l1 = 2048 + wave * 512;   // A buffer half 1

    floatx4 acc1[4][2], acc3[4][2];
#pragma unroll
    for (int a = 0; a < 4; a++)
#pragma unroll
        for (int b = 0; b < 2; b++) {
            acc1[a][b] = (floatx4){0.f, 0.f, 0.f, 0.f};
            acc3[a][b] = (floatx4){0.f, 0.f, 0.f, 0.f};
        }

    // 4 global_load_lds per thread per tile => vmcnt unit = 4/tile
    auto stage = [&](int t, int b) {
        const int kk = t * 32;
        async_copy16(gA0 + kk, sA + b * 4096 + l0);
        async_copy16(gA1 + kk, sA + b * 4096 + l1);
        async_copy16(gB1 + kk, sB1 + b * 2048 + l0);
        async_copy16(gB3 + kk, sB3 + b * 2048 + l0);
    };
    auto compute = [&](int b) {
        const unsigned short* pa = sA + b * 4096;
        const unsigned short* p1 = sB1 + b * 2048;
        const unsigned short* p3 = sB3 + b * 2048;
        short8 af[4];
#pragma unroll
        for (int mt = 0; mt < 4; mt++) {
            const int ra = wy * 64 + mt * 16 + tl;
            af[mt] = *(const short8*)(pa + ra * 32 + (quad ^ ((ra >> 1) & 3)) * 8);
        }
#pragma unroll
        for (int nt = 0; nt < 2; nt++) {
            const int rb = wx * 32 + nt * 16 + tl;
            const int cb = (quad ^ ((rb >> 1) & 3)) * 8;
            short8 b1 = *(const short8*)(p1 + rb * 32 + cb);
            short8 b3 = *(const short8*)(p3 + rb * 32 + cb);
#pragma unroll
            for (int mt = 0; mt < 4; mt++) {
                acc1[mt][nt] = __builtin_amdgcn_mfma_f32_16x16x32_bf16(af[mt], b1, acc1[mt][nt], 0, 0, 0);
                acc3[mt][nt] = __builtin_amdgcn_mfma_f32_16x16x32_bf16(af[mt], b3, acc3[mt][nt], 0, 0, 0);
            }
        }
    };

    // prologue: 2 tiles in flight
    stage(0, 0);
    stage(1, 1);

    int bc = 0;   // buffer holding current tile (= k % 3)
    for (int k = 0; k < NT1 - 1; ++k) {
        asm volatile("s_waitcnt vmcnt(4)" ::: "memory");   // tile k landed; k+1 in flight
        __builtin_amdgcn_s_barrier();                      // all waves' tile-k writes visible
        if (k + 2 < NT1) {
            int bp = bc + 2; if (bp >= 3) bp -= 3;         // (k+2) % 3
            stage(k + 2, bp);                              // overwrites buffer read at k-1
        }
        compute(bc);
        bc = (bc == 2) ? 0 : bc + 1;
    }
    asm volatile("s_waitcnt vmcnt(0)" ::: "memory");       // last tile
    __builtin_amdgcn_s_barrier();
    compute(bc);

    const int hbase = offsets[e];
#pragma unroll
    for (int mt = 0; mt < 4; mt++)
#pragma unroll
        for (int nt = 0; nt < 2; nt++)
#pragma unroll
            for (int i = 0; i < 4; i++) {
                int r = tm * 128 + wy * 64 + mt * 16 + quad * 4 + i;  // row=(lane>>4)*4+reg
                if (r < cnt) {
                    int c = tn * 64 + wx * 32 + nt * 16 + tl;         // col=lane&15
                    float z1 = acc1[mt][nt][i];
                    float z3 = acc3[mt][nt][i];
                    float hv = (z1 / (1.f + expf(-z1))) * z3;
                    h[(size_t)(hbase + r) * F_DIM + c] = f2bf(hv);
                }
            }
}

// gemm2f: hout = h @ w2^T (unscaled), compact rows; 128x128 tile
__global__ __launch_bounds__(256, 3) void gemm2f_kernel(
    const unsigned short* __restrict__ h, const unsigned short* __restrict__ w2b,
    const int* __restrict__ counts, const int* __restrict__ offsets,
    float* __restrict__ hout)
{
    // grid = (32, 8, 8) = 2048 blocks; chunk of 256 == one expert
    const int lin = blockIdx.x + 32 * (blockIdx.y + 8 * blockIdx.z);
    const int w = (lin & 7) * 256 + (lin >> 3);
    const int tm = w & 31;
    const int tn = (w >> 5) & 7;
    const int e  = w >> 8;

    const int cnt = counts[e];
    if (tm * 128 >= cnt) return;
    const int tid = threadIdx.x;

    __shared__ unsigned short sA[3 * 128 * 32];   // 24KB
    __shared__ unsigned short sB[3 * 128 * 32];   // 24KB

    const int hbase = offsets[e];
    const int wave = tid >> 6, lane = tid & 63;
    const int wx = wave & 1, wy = wave >> 1;
    const int quad = lane >> 4, tl = lane & 15;

    const int sr = tid >> 2;
    const int scw = ((tid & 3) ^ ((sr >> 1) & 3)) * 8;
    int ra0 = hbase + tm * 128 + sr;      if (ra0 > TOTROW - 1) ra0 = TOTROW - 1;
    int ra1 = hbase + tm * 128 + sr + 64; if (ra1 > TOTROW - 1) ra1 = TOTROW - 1;
    const unsigned short* gA0 = h + (size_t)ra0 * F_DIM + scw;
    const unsigned short* gA1 = h + (size_t)ra1 * F_DIM + scw;
    const unsigned short* gB0 = w2b + ((size_t)e * D_DIM + (size_t)tn * 128 + sr) * F_DIM + scw;
    const unsigned short* gB1 = gB0 + (size_t)64 * F_DIM;

    const int l0 = wave * 512;
    const int l1 = 2048 + wave * 512;

    floatx4 acc[4][4];
#pragma unroll
    for (int a = 0; a < 4; a++)
#pragma unroll
        for (int b = 0; b < 4; b++) acc[a][b] = (floatx4){0.f, 0.f, 0.f, 0.f};

    auto stage = [&](int t, int b) {
        const int kk = t * 32;
        async_copy16(gA0 + kk, sA + b * 4096 + l0);
        async_copy16(gA1 + kk, sA + b * 4096 + l1);
        async_copy16(gB0 + kk, sB + b * 4096 + l0);
        async_copy16(gB1 + kk, sB + b * 4096 + l1);
    };
    auto compute = [&](int b) {
        const unsigned short* pa = sA + b * 4096;
        const unsigned short* pb = sB + b * 4096;
        short8 af[4];
#pragma unroll
        for (int mt = 0; mt < 4; mt++) {
            const int ra = wy * 64 + mt * 16 + tl;
            af[mt] = *(const short8*)(pa + ra * 32 + (quad ^ ((ra >> 1) & 3)) * 8);
        }
#pragma unroll
        for (int nt = 0; nt < 4; nt++) {
            const int rb = wx * 64 + nt * 16 + tl;
            short8 bf = *(const short8*)(pb + rb * 32 + (quad ^ ((rb >> 1) & 3)) * 8);
#pragma unroll
            for (int mt = 0; mt < 4; mt++)
                acc[mt][nt] = __builtin_amdgcn_mfma_f32_16x16x32_bf16(af[mt], bf, acc[mt][nt], 0, 0, 0);
        }
    };

    stage(0, 0);
    stage(1, 1);

    int bc = 0;
    for (int k = 0; k < NT2 - 1; ++k) {
        asm volatile("s_waitcnt vmcnt(4)" ::: "memory");
        __builtin_amdgcn_s_barrier();
        if (k + 2 < NT2) {
            int bp = bc + 2; if (bp >= 3) bp -= 3;
            stage(k + 2, bp);
        }
        compute(bc);
        bc = (bc == 2) ? 0 : bc + 1;
    }
    asm volatile("s_waitcnt vmcnt(0)" ::: "memory");
    __builtin_amdgcn_s_barrier();
    compute(bc);

#pragma unroll
    for (int mt = 0; mt < 4; mt++)
#pragma unroll
        for (int nt = 0; nt < 4; nt++)
#pragma unroll
            for (int i = 0; i < 4; i++) {
                int r = tm * 128 + wy * 64 + mt * 16 + quad * 4 + i;
                if (r < cnt) {
                    int c = tn * 128 + wx * 64 + nt * 16 + tl;
                    hout[(size_t)(hbase + r) * D_DIM + c] = acc[mt][nt][i];
                }
            }
}

// combine: out[t] = w0*hout[slot0] + w1*hout[slot1]
__global__ __launch_bounds__(256) void combine_kernel(
    const float* __restrict__ hout, const int* __restrict__ offsets,
    const int* __restrict__ se, const int* __restrict__ sp, const float* __restrict__ sw,
    float* __restrict__ out)
{
    const int t = blockIdx.x;
    const int tid = threadIdx.x;
    int s0 = offsets[se[2 * t]] + sp[2 * t];
    int s1 = offsets[se[2 * t + 1]] + sp[2 * t + 1];
    float w0 = sw[2 * t], w1 = sw[2 * t + 1];
    float4 a = ((const float4*)(hout + (size_t)s0 * D_DIM))[tid];
    float4 b = ((const float4*)(hout + (size_t)s1 * D_DIM))[tid];
    float4 o;
    o.x = w0 * a.x + w1 * b.x; o.y = w0 * a.y + w1 * b.y;
    o.z = w0 * a.z + w1 * b.z; o.w = w0 * a.w + w1 * b.w;
    ((float4*)(out + (size_t)t * D_DIM))[tid] = o;
}

// ================= FALLBACK PATH (R1-proven, ~64.3MB ws) =================
#define BM 64
#define BN 64
#define LDSP 40

__global__ __launch_bounds__(256) void gemm1s_kernel(
    const float* __restrict__ x, const float* __restrict__ w1,
    const float* __restrict__ w3,
    const int* __restrict__ counts, const int* __restrict__ offsets,
    const int* __restrict__ tok, unsigned short* __restrict__ h)
{
    const int e = blockIdx.z;
    const int cnt = counts[e];
    const int tm = blockIdx.x;
    if (tm * BM >= cnt) return;
    const int tn = blockIdx.y;
    const int tid = threadIdx.x;

    __shared__ unsigned short As[BM][LDSP];
    __shared__ unsigned short B1s[BN][LDSP];
    __shared__ unsigned short B3s[BN][LDSP];
    __shared__ int tokS[BM];

    if (tid < BM) {
        int r = tm * BM + tid;
        tokS[tid] = (r < cnt) ? tok[e * MAXTOK + r] : -1;
    }
    __syncthreads();

    const int wave = tid >> 6;
    const int lane = tid & 63;
    const int wx = wave & 1, wy = wave >> 1;
    const int quad = lane >> 4, tl = lane & 15;

    floatx4 acc1[2][2], acc3[2][2];
#pragma unroll
    for (int a = 0; a < 2; a++)
#pragma unroll
        for (int b = 0; b < 2; b++) {
            acc1[a][b] = (floatx4){0.f, 0.f, 0.f, 0.f};
            acc3[a][b] = (floatx4){0.f, 0.f, 0.f, 0.f};
        }

    const float* w1e = w1 + (size_t)e * F_DIM * D_DIM + (size_t)(tn * BN) * D_DIM;
    const float* w3e = w3 + (size_t)e * F_DIM * D_DIM + (size_t)(tn * BN) * D_DIM;

    for (int kk = 0; kk < D_DIM; kk += 32) {
#pragma unroll
        for (int i = 0; i < 2; i++) {
            int j = tid + i * 256;
            int r = j >> 3, c4 = j & 7;
            float4 v = make_float4(0.f, 0.f, 0.f, 0.f);
            int tkn = tokS[r];
            if (tkn >= 0) v = *(const float4*)(x + (size_t)tkn * D_DIM + kk + c4 * 4);
            unsigned short* dst = &As[r][c4 * 4];
            dst[0] = f2bf(v.x); dst[1] = f2bf(v.y); dst[2] = f2bf(v.z); dst[3] = f2bf(v.w);
        }
#pragma unroll
        for (int i = 0; i < 2; i++) {
            int j = tid + i * 256;
            int r = j >> 3, c4 = j & 7;
            const float4 v1 = *(const float4*)(w1e + (size_t)r * D_DIM + kk + c4 * 4);
            const float4 v3 = *(const float4*)(w3e + (size_t)r * D_DIM + kk + c4 * 4);
            unsigned short* d1 = &B1s[r][c4 * 4];
            d1[0] = f2bf(v1.x); d1[1] = f2bf(v1.y); d1[2] = f2bf(v1.z); d1[3] = f2bf(v1.w);
            unsigned short* d3 = &B3s[r][c4 * 4];
            d3[0] = f2bf(v3.x); d3[1] = f2bf(v3.y); d3[2] = f2bf(v3.z); d3[3] = f2bf(v3.w);
        }
        __syncthreads();

        short8 a0 = *(const short8*)&As[wy * 32 + tl][quad * 8];
        short8 a1 = *(const short8*)&As[wy * 32 + 16 + tl][quad * 8];
        short8 b1a = *(const short8*)&B1s[wx * 32 + tl][quad * 8];
        short8 b1b = *(const short8*)&B1s[wx * 32 + 16 + tl][quad * 8];
        short8 b3a = *(const short8*)&B3s[wx * 32 + tl][quad * 8];
        short8 b3b = *(const short8*)&B3s[wx * 32 + 16 + tl][quad * 8];

        acc1[0][0] = __builtin_amdgcn_mfma_f32_16x16x32_bf16(a0, b1a, acc1[0][0], 0, 0, 0);
        acc1[0][1] = __builtin_amdgcn_mfma_f32_16x16x32_bf16(a0, b1b, acc1[0][1], 0, 0, 0);
        acc1[1][0] = __builtin_amdgcn_mfma_f32_16x16x32_bf16(a1, b1a, acc1[1][0], 0, 0, 0);
        acc1[1][1] = __builtin_amdgcn_mfma_f32_16x16x32_bf16(a1, b1b, acc1[1][1], 0, 0, 0);
        acc3[0][0] = __builtin_amdgcn_mfma_f32_16x16x32_bf16(a0, b3a, acc3[0][0], 0, 0, 0);
        acc3[0][1] = __builtin_amdgcn_mfma_f32_16x16x32_bf16(a0, b3b, acc3[0][1], 0, 0, 0);
        acc3[1][0] = __builtin_amdgcn_mfma_f32_16x16x32_bf16(a1, b3a, acc3[1][0], 0, 0, 0);
        acc3[1][1] = __builtin_amdgcn_mfma_f32_16x16x32_bf16(a1, b3b, acc3[1][1], 0, 0, 0);
        __syncthreads();
    }

    const int hbase = offsets[e];
#pragma unroll
    for (int mt = 0; mt < 2; mt++)
#pragma unroll
        for (int nt = 0; nt < 2; nt++)
#pragma unroll
            for (int i = 0; i < 4; i++) {
                int rl = wy * 32 + mt * 16 + quad * 4 + i;
                int r = tm * BM + rl;
                if (r < cnt) {
                    int c = tn * BN + wx * 32 + nt * 16 + tl;
                    float z1 = acc1[mt][nt][i];
                    float z3 = acc3[mt][nt][i];
                    float hv = (z1 / (1.f + expf(-z1))) * z3;
                    h[(size_t)(hbase + r) * F_DIM + c] = f2bf(hv);
                }
            }
}

__global__ __launch_bounds__(256) void gemm2s_kernel(
    const unsigned short* __restrict__ h, const float* __restrict__ w2,
    const int* __restrict__ counts, const int* __restrict__ offsets,
    const int* __restrict__ tok, const float* __restrict__ rw,
    float* __restrict__ out)
{
    const int e = blockIdx.z;
    const int cnt = counts[e];
    const int tm = blockIdx.x;
    if (tm * BM >= cnt) return;
    const int tn = blockIdx.y;
    const int tid = threadIdx.x;

    __shared__ unsigned short As[BM][LDSP];
    __shared__ unsigned short Bs[BN][LDSP];
    __shared__ int tokS[BM];
    __shared__ float rwS[BM];

    const int hbase = offsets[e];
    if (tid < BM) {
        int r = tm * BM + tid;
        tokS[tid] = (r < cnt) ? tok[e * MAXTOK + r] : -1;
        rwS[tid] = (r < cnt) ? rw[e * MAXTOK + r] : 0.f;
    }
    __syncthreads();

    const int wave = tid >> 6, lane = tid & 63;
    const int wx = wave & 1, wy = wave >> 1;
    const int quad = lane >> 4, tl = lane & 15;

    floatx4 acc[2][2];
#pragma unroll
    for (int a = 0; a < 2; a++)
#pragma unroll
        for (int b = 0; b < 2; b++) acc[a][b] = (floatx4){0.f, 0.f, 0.f, 0.f};

    const float* w2e = w2 + (size_t)e * D_DIM * F_DIM + (size_t)(tn * BN) * F_DIM;
    const unsigned short* hA = h + (size_t)(hbase + tm * BM) * F_DIM;

    for (int kk = 0; kk < F_DIM; kk += 32) {
        {
            int r = tid >> 2, c8 = tid & 3;
            short8 v = {0, 0, 0, 0, 0, 0, 0, 0};
            if (tm * BM + r < cnt) v = *(const short8*)(hA + (size_t)r * F_DIM + kk + c8 * 8);
            *(short8*)&As[r][c8 * 8] = v;
        }
#pragma unroll
        for (int i = 0; i < 2; i++) {
            int j = tid + i * 256;
            int r = j >> 3, c4 = j & 7;
            const float4 v = *(const float4*)(w2e + (size_t)r * F_DIM + kk + c4 * 4);
            unsigned short* dst = &Bs[r][c4 * 4];
            dst[0] = f2bf(v.x); dst[1] = f2bf(v.y); dst[2] = f2bf(v.z); dst[3] = f2bf(v.w);
        }
        __syncthreads();

        short8 a0 = *(const short8*)&As[wy * 32 + tl][quad * 8];
        short8 a1 = *(const short8*)&As[wy * 32 + 16 + tl][quad * 8];
        short8 b0 = *(const short8*)&Bs[wx * 32 + tl][quad * 8];
        short8 b1 = *(const short8*)&Bs[wx * 32 + 16 + tl][quad * 8];

        acc[0][0] = __builtin_amdgcn_mfma_f32_16x16x32_bf16(a0, b0, acc[0][0], 0, 0, 0);
        acc[0][1] = __builtin_amdgcn_mfma_f32_16x16x32_bf16(a0, b1, acc[0][1], 0, 0, 0);
        acc[1][0] = __builtin_amdgcn_mfma_f32_16x16x32_bf16(a1, b0, acc[1][0], 0, 0, 0);
        acc[1][1] = __builtin_amdgcn_mfma_f32_16x16x32_bf16(a1, b1, acc[1][1], 0, 0, 0);
        __syncthreads();
    }

#pragma unroll
    for (int mt = 0; mt < 2; mt++)
#pragma unroll
        for (int nt = 0; nt < 2; nt++)
#pragma unroll
            for (int i = 0; i < 4; i++) {
                int rl = wy * 32 + mt * 16 + quad * 4 + i;
                int r = tm * BM + rl;
                if (r < cnt) {
                    int t = tokS[rl];
                    float w = rwS[rl];
                    int c = tn * BN + wx * 32 + nt * 16 + tl;
                    atomicAdd(&out[(size_t)t * D_DIM + c], acc[mt][nt][i] * w);
                }
            }
}

// ================= launch =================
extern "C" void kernel_launch(void* const* d_in, const int* in_sizes, int n_in,
                              void* d_out, int out_size, void* d_ws, size_t ws_size,
                              hipStream_t stream)
{
    const float* x  = (const float*)d_in[0];
    const float* gw = (const float*)d_in[1];
    const float* w1 = (const float*)d_in[2];
    const float* w3 = (const float*)d_in[3];
    const float* w2 = (const float*)d_in[4];
    float* out = (float*)d_out;

    // common small region
    char* p = (char*)d_ws;
    int* counts  = (int*)p;            p += 64;
    int* offsets = (int*)p;            p += 64;
    int* tok     = (int*)p;            p += (size_t)E_NUM * MAXTOK * 4;   // 128KB
    float* rw    = (float*)p;          p += (size_t)E_NUM * MAXTOK * 4;   // 128KB

    // fast-path extra regions
    const size_t SEL = (size_t)2 * T_TOK * 4;              // 32KB each
    const size_t XB  = (size_t)T_TOK * D_DIM * 2;          // 8MiB
    const size_t WB  = (size_t)E_NUM * F_DIM * D_DIM * 2;  // 64MiB each
    const size_t HB  = (size_t)TOTROW * F_DIM * 2;         // 64MiB
    const size_t HO  = (size_t)TOTROW * D_DIM * 4;         // 32MiB
    const size_t small = (size_t)(p - (char*)d_ws);
    const size_t need_fast = small + 3 * SEL + XB + 3 * WB + HB + HO;

    if (ws_size >= need_fast) {
        int* se = (int*)p;               p += SEL;
        int* sp = (int*)p;               p += SEL;
        float* sw = (float*)p;           p += SEL;
        unsigned short* xb  = (unsigned short*)p;  p += XB;
        unsigned short* w1b = (unsigned short*)p;  p += WB;
        unsigned short* w3b = (unsigned short*)p;  p += WB;
        unsigned short* w2b = (unsigned short*)p;  p += WB;
        unsigned short* h   = (unsigned short*)p;  p += HB;
        float* hout = (float*)p;

        hipMemsetAsync(counts, 0, 64, stream);
        cvt_kernel<<<2048, 256, 0, stream>>>(x,  xb,  T_TOK * D_DIM / 8);
        cvt_kernel<<<8192, 256, 0, stream>>>(w1, w1b, E_NUM * F_DIM * D_DIM / 8);
        cvt_kernel<<<8192, 256, 0, stream>>>(w3, w3b, E_NUM * F_DIM * D_DIM / 8);
        cvt_kernel<<<8192, 256, 0, stream>>>(w2, w2b, E_NUM * F_DIM * D_DIM / 8);
        router_kernel<<<T_TOK, 64, 0, stream>>>(x, gw, counts, tok, rw, se, sp, sw);
        prefix_kernel<<<1, 64, 0, stream>>>(counts, offsets);
        dim3 g1(T_TOK / 128, F_DIM / 64, E_NUM);
        gemm1f_kernel<<<g1, 256, 0, stream>>>(xb, w1b, w3b, counts, offsets, tok, h);
        dim3 g2(T_TOK / 128, D_DIM / 128, E_NUM);
        gemm2f_kernel<<<g2, 256, 0, stream>>>(h, w2b, counts, offsets, hout);
        combine_kernel<<<T_TOK, 256, 0, stream>>>(hout, offsets, se, sp, sw, out);
    } else {
        // R1-proven fallback (~64.5MB ws)
        unsigned short* h = (unsigned short*)p;
        // router's se/sp/sw scribble into h region; gemm1s rewrites all of h afterwards
        int* se = (int*)h;
        int* sp = se + 2 * T_TOK;
        float* sw = (float*)(sp + 2 * T_TOK);

        hipMemsetAsync(counts, 0, 64, stream);
        hipMemsetAsync(d_out, 0, (size_t)out_size * sizeof(float), stream);
        router_kernel<<<T_TOK, 64, 0, stream>>>(x, gw, counts, tok, rw, se, sp, sw);
        prefix_kernel<<<1, 64, 0, stream>>>(counts, offsets);
        dim3 g1(T_TOK / BM, F_DIM / BN, E_NUM);
        gemm1s_kernel<<<g1, 256, 0, stream>>>(x, w1, w3, counts, offsets, tok, h);
        dim3 g2(T_TOK / BM, D_DIM / BN, E_NUM);
        gemm2s_kernel<<<g2, 256, 0, stream>>>(h, w2, counts, offsets, tok, rw, out);
    }
}

// Round 4
// 866.377 us; speedup vs baseline: 1.0676x; 1.0676x over previous
//
#include <hip/hip_runtime.h>
#include <hip/hip_bf16.h>
#include <stdint.h>

// Problem constants (fixed by setup_inputs)
#define T_TOK 4096   // B*S tokens
#define D_DIM 1024
#define F_DIM 4096
#define E_NUM 8
#define MAXTOK 4096  // worst-case tokens per expert
#define TOTROW 8192  // total gathered rows = 2*T_TOK

typedef __attribute__((ext_vector_type(8))) short short8;
typedef __attribute__((ext_vector_type(4))) float floatx4;

__device__ __forceinline__ unsigned short f2bf(float f) {
    union { float f; unsigned u; } v; v.f = f;
    unsigned u = v.u;
    u += 0x7fff + ((u >> 16) & 1);   // round-to-nearest-even
    return (unsigned short)(u >> 16);
}

// async global -> LDS, 16B per lane. LDS dest must be wave-uniform base; HW adds lane*16.
__device__ __forceinline__ void async_copy16(const unsigned short* g, unsigned short* l) {
    __builtin_amdgcn_global_load_lds(
        (__attribute__((address_space(1))) void*)(g),
        (__attribute__((address_space(3))) void*)(l), 16, 0, 0);
}

// ---------------- fp32 -> bf16 bulk convert (grid-stride, 8 elems/thread) ----------------
__global__ __launch_bounds__(256) void cvt_kernel(
    const float* __restrict__ src, unsigned short* __restrict__ dst, int n8)
{
    int i = blockIdx.x * blockDim.x + threadIdx.x;
    int stride = gridDim.x * blockDim.x;
    for (; i < n8; i += stride) {
        const float4* s = (const float4*)src + 2 * (size_t)i;
        float4 a = s[0], b = s[1];
        short8 o;
        o[0] = (short)f2bf(a.x); o[1] = (short)f2bf(a.y);
        o[2] = (short)f2bf(a.z); o[3] = (short)f2bf(a.w);
        o[4] = (short)f2bf(b.x); o[5] = (short)f2bf(b.y);
        o[6] = (short)f2bf(b.z); o[7] = (short)f2bf(b.w);
        *((short8*)dst + (size_t)i) = o;
    }
}

// ---------------- router: logits -> top2 -> scatter (float4-vectorized) ----------------
__global__ __launch_bounds__(64) void router_kernel(
    const float* __restrict__ x, const float* __restrict__ gw,
    int* __restrict__ counts, int* __restrict__ tok, float* __restrict__ rw,
    int* __restrict__ se, int* __restrict__ sp, float* __restrict__ sw)
{
    const int t = blockIdx.x;
    const int l = threadIdx.x;
    const float4* xr = (const float4*)(x + (size_t)t * D_DIM);
    float acc[E_NUM];
#pragma unroll
    for (int e = 0; e < E_NUM; e++) acc[e] = 0.f;
#pragma unroll
    for (int i = 0; i < D_DIM / 4 / 64; i++) {
        float4 xv = xr[l + i * 64];
#pragma unroll
        for (int e = 0; e < E_NUM; e++) {
            float4 gv = ((const float4*)(gw + e * D_DIM))[l + i * 64];
            acc[e] += xv.x * gv.x + xv.y * gv.y + xv.z * gv.z + xv.w * gv.w;
        }
    }
#pragma unroll
    for (int e = 0; e < E_NUM; e++) {
        float a = acc[e];
        for (int off = 32; off > 0; off >>= 1) a += __shfl_xor(a, off, 64);
        acc[e] = a;
    }
    if (l == 0) {
        int e0 = 0;
#pragma unroll
        for (int e = 1; e < E_NUM; e++) if (acc[e] > acc[e0]) e0 = e;
        int e1 = (e0 == 0) ? 1 : 0;
#pragma unroll
        for (int e = 0; e < E_NUM; e++) if (e != e0 && acc[e] > acc[e1]) e1 = e;
        float w0 = 1.f / (1.f + expf(acc[e1] - acc[e0]));   // renorm top-2; denom cancels
        float w1 = 1.f - w0;
        int p0 = atomicAdd(&counts[e0], 1);
        tok[e0 * MAXTOK + p0] = t; rw[e0 * MAXTOK + p0] = w0;
        int p1 = atomicAdd(&counts[e1], 1);
        tok[e1 * MAXTOK + p1] = t; rw[e1 * MAXTOK + p1] = w1;
        se[2 * t] = e0; sp[2 * t] = p0; sw[2 * t] = w0;
        se[2 * t + 1] = e1; sp[2 * t + 1] = p1; sw[2 * t + 1] = w1;
    }
}

__global__ void prefix_kernel(const int* __restrict__ counts, int* __restrict__ offsets)
{
    if (threadIdx.x == 0 && blockIdx.x == 0) {
        int run = 0;
        for (int e = 0; e < E_NUM; e++) { offsets[e] = run; run += counts[e]; }
    }
}

// ================= FAST PATH: R2 2-phase dbuf GEMMs at 4 waves/SIMD =================
//
// R4: R3's counted-vmcnt pipeline regressed (313 vs 274 us) -> reverted to the proven
// R2 2-phase loop. The REAL bottleneck found in post-mortem: unified regs = 68 VGPR +
// 64 AGPR acc = 132 > 128 -> allocation rounds to 192-granule -> 2 waves/SIMD
// (Occupancy 25%). Fix: __launch_bounds__(256,4) caps unified file at 128 regs ->
// 4 waves/SIMD / 4 blocks/CU. Helped by 32-bit element offsets off SGPR bases
// (replaces four 64b pointers; B1/B3 share one offset).
// T2 chunk-XOR swizzle retained (bank conflicts measured 0). Expert-per-XCD swizzle
// retained (FETCH ~= single-pass weights).

// gemm1f: h = silu(x@w1^T) * (x@w3^T), gathered bf16 rows, 128x64 tile, dbuf
__global__ __launch_bounds__(256, 4) void gemm1f_kernel(
    const unsigned short* __restrict__ xb,
    const unsigned short* __restrict__ w1b, const unsigned short* __restrict__ w3b,
    const int* __restrict__ counts, const int* __restrict__ offsets,
    const int* __restrict__ tok, unsigned short* __restrict__ h)
{
    // grid = (32, 64, 8) = 16384 blocks; XCD k == expert k, tm fastest
    const int lin = blockIdx.x + 32 * (blockIdx.y + 64 * blockIdx.z);
    const int w = (lin & 7) * 2048 + (lin >> 3);
    const int tm = w & 31;
    const int tn = (w >> 5) & 63;
    const int e  = w >> 11;

    const int cnt = counts[e];
    if (tm * 128 >= cnt) return;          // uniform early exit
    const int tid = threadIdx.x;

    __shared__ unsigned short sA[2][128 * 32];   // 16KB
    __shared__ unsigned short sB1[2][64 * 32];   // 8KB
    __shared__ unsigned short sB3[2][64 * 32];   // 8KB
    __shared__ int tokS[128];

    if (tid < 128) {
        int r = tm * 128 + tid;
        tokS[tid] = tok[e * MAXTOK + (r < cnt ? r : cnt - 1)];  // clamp; masked at store
    }
    __syncthreads();

    const int wave = tid >> 6, lane = tid & 63;
    const int wx = wave & 1, wy = wave >> 1;
    const int quad = lane >> 4, tl = lane & 15;

    // staging: row = tid>>2 (0..63), dest chunk = tid&3; SOURCE chunk swizzled (T2)
    const int sr = tid >> 2;
    const int scw = ((tid & 3) ^ ((sr >> 1) & 3)) * 8;
    // 32-bit element offsets off SGPR bases (all arrays < 2^32 elems)
    const unsigned offA0 = (unsigned)tokS[sr] * D_DIM + scw;
    const unsigned offA1 = (unsigned)tokS[sr + 64] * D_DIM + scw;
    const unsigned offB  = ((unsigned)e * F_DIM + (unsigned)tn * 64 + sr) * D_DIM + scw;

    // wave-uniform LDS staging bases (elems)
    const int l0 = wave * 512;
    const int l1 = 2048 + wave * 512;

    floatx4 acc1[4][2], acc3[4][2];
#pragma unroll
    for (int a = 0; a < 4; a++)
#pragma unroll
        for (int b = 0; b < 2; b++) {
            acc1[a][b] = (floatx4){0.f, 0.f, 0.f, 0.f};
            acc3[a][b] = (floatx4){0.f, 0.f, 0.f, 0.f};
        }

    // prologue: stage tile 0 into buf 0
    async_copy16(xb + offA0, sA[0] + l0);
    async_copy16(xb + offA1, sA[0] + l1);
    async_copy16(w1b + offB, sB1[0] + l0);
    async_copy16(w3b + offB, sB3[0] + l0);
    __syncthreads();   // vmcnt(0) drain -> tile 0 visible

    int cur = 0;
    for (int kk = 0; kk < D_DIM; kk += 32) {
        // issue next tile's loads FIRST — they fly under ds_read+MFMA of this tile
        const int nk = kk + 32;
        if (nk < D_DIM) {
            async_copy16(xb + offA0 + nk, sA[cur ^ 1] + l0);
            async_copy16(xb + offA1 + nk, sA[cur ^ 1] + l1);
            async_copy16(w1b + offB + nk, sB1[cur ^ 1] + l0);
            async_copy16(w3b + offB + nk, sB3[cur ^ 1] + l0);
        }

        short8 af[4];
#pragma unroll
        for (int mt = 0; mt < 4; mt++) {
            const int ra = wy * 64 + mt * 16 + tl;
            af[mt] = *(const short8*)(sA[cur] + ra * 32 + (quad ^ ((ra >> 1) & 3)) * 8);
        }
#pragma unroll
        for (int nt = 0; nt < 2; nt++) {
            const int rb = wx * 32 + nt * 16 + tl;
            const int cb = (quad ^ ((rb >> 1) & 3)) * 8;
            short8 b1 = *(const short8*)(sB1[cur] + rb * 32 + cb);
            short8 b3 = *(const short8*)(sB3[cur] + rb * 32 + cb);
#pragma unroll
            for (int mt = 0; mt < 4; mt++) {
                acc1[mt][nt] = __builtin_amdgcn_mfma_f32_16x16x32_bf16(af[mt], b1, acc1[mt][nt], 0, 0, 0);
                acc3[mt][nt] = __builtin_amdgcn_mfma_f32_16x16x32_bf16(af[mt], b3, acc3[mt][nt], 0, 0, 0);
            }
        }
        __syncthreads();   // reads of buf[cur] done by all waves; buf[cur^1] staged & visible
        cur ^= 1;
    }

    const int hbase = offsets[e];
#pragma unroll
    for (int mt = 0; mt < 4; mt++)
#pragma unroll
        for (int nt = 0; nt < 2; nt++)
#pragma unroll
            for (int i = 0; i < 4; i++) {
                int r = tm * 128 + wy * 64 + mt * 16 + quad * 4 + i;  // row=(lane>>4)*4+reg
                if (r < cnt) {
                    int c = tn * 64 + wx * 32 + nt * 16 + tl;         // col=lane&15
                    float z1 = acc1[mt][nt][i];
                    float z3 = acc3[mt][nt][i];
                    float hv = (z1 / (1.f + expf(-z1))) * z3;
                    h[(size_t)(hbase + r) * F_DIM + c] = f2bf(hv);
                }
            }
}

// gemm2f: hout = h @ w2^T (unscaled), compact rows; 128x128 tile, dbuf
__global__ __launch_bounds__(256, 4) void gemm2f_kernel(
    const unsigned short* __restrict__ h, const unsigned short* __restrict__ w2b,
    const int* __restrict__ counts, const int* __restrict__ offsets,
    float* __restrict__ hout)
{
    // grid = (32, 8, 8) = 2048 blocks; chunk of 256 == one expert
    const int lin = blockIdx.x + 32 * (blockIdx.y + 8 * blockIdx.z);
    const int w = (lin & 7) * 256 + (lin >> 3);
    const int tm = w & 31;
    const int tn = (w >> 5) & 7;
    const int e  = w >> 8;

    const int cnt = counts[e];
    if (tm * 128 >= cnt) return;
    const int tid = threadIdx.x;

    __shared__ unsigned short sA[2][128 * 32];
    __shared__ unsigned short sB[2][128 * 32];

    const int hbase = offsets[e];
    const int wave = tid >> 6, lane = tid & 63;
    const int wx = wave & 1, wy = wave >> 1;
    const int quad = lane >> 4, tl = lane & 15;

    const int sr = tid >> 2;
    const int scw = ((tid & 3) ^ ((sr >> 1) & 3)) * 8;
    int ra0 = hbase + tm * 128 + sr;      if (ra0 > TOTROW - 1) ra0 = TOTROW - 1;
    int ra1 = ra0 + 64;                   if (ra1 > TOTROW - 1) ra1 = TOTROW - 1;
    const unsigned offA0 = (unsigned)ra0 * F_DIM + scw;
    const unsigned offA1 = (unsigned)ra1 * F_DIM + scw;
    const unsigned offB  = ((unsigned)e * D_DIM + (unsigned)tn * 128 + sr) * F_DIM + scw;
    const unsigned offB1 = offB + 64u * F_DIM;

    const int l0 = wave * 512;
    const int l1 = 2048 + wave * 512;

    floatx4 acc[4][4];
#pragma unroll
    for (int a = 0; a < 4; a++)
#pragma unroll
        for (int b = 0; b < 4; b++) acc[a][b] = (floatx4){0.f, 0.f, 0.f, 0.f};

    // prologue
    async_copy16(h + offA0, sA[0] + l0);
    async_copy16(h + offA1, sA[0] + l1);
    async_copy16(w2b + offB, sB[0] + l0);
    async_copy16(w2b + offB1, sB[0] + l1);
    __syncthreads();

    int cur = 0;
    for (int kk = 0; kk < F_DIM; kk += 32) {
        const int nk = kk + 32;
        if (nk < F_DIM) {
            async_copy16(h + offA0 + nk, sA[cur ^ 1] + l0);
            async_copy16(h + offA1 + nk, sA[cur ^ 1] + l1);
            async_copy16(w2b + offB + nk, sB[cur ^ 1] + l0);
            async_copy16(w2b + offB1 + nk, sB[cur ^ 1] + l1);
        }

        short8 af[4];
#pragma unroll
        for (int mt = 0; mt < 4; mt++) {
            const int ra = wy * 64 + mt * 16 + tl;
            af[mt] = *(const short8*)(sA[cur] + ra * 32 + (quad ^ ((ra >> 1) & 3)) * 8);
        }
#pragma unroll
        for (int nt = 0; nt < 4; nt++) {
            const int rb = wx * 64 + nt * 16 + tl;
            short8 bf = *(const short8*)(sB[cur] + rb * 32 + (quad ^ ((rb >> 1) & 3)) * 8);
#pragma unroll
            for (int mt = 0; mt < 4; mt++)
                acc[mt][nt] = __builtin_amdgcn_mfma_f32_16x16x32_bf16(af[mt], bf, acc[mt][nt], 0, 0, 0);
        }
        __syncthreads();
        cur ^= 1;
    }

#pragma unroll
    for (int mt = 0; mt < 4; mt++)
#pragma unroll
        for (int nt = 0; nt < 4; nt++)
#pragma unroll
            for (int i = 0; i < 4; i++) {
                int r = tm * 128 + wy * 64 + mt * 16 + quad * 4 + i;
                if (r < cnt) {
                    int c = tn * 128 + wx * 64 + nt * 16 + tl;
                    hout[(size_t)(hbase + r) * D_DIM + c] = acc[mt][nt][i];
                }
            }
}

// combine: out[t] = w0*hout[slot0] + w1*hout[slot1]
__global__ __launch_bounds__(256) void combine_kernel(
    const float* __restrict__ hout, const int* __restrict__ offsets,
    const int* __restrict__ se, const int* __restrict__ sp, const float* __restrict__ sw,
    float* __restrict__ out)
{
    const int t = blockIdx.x;
    const int tid = threadIdx.x;
    int s0 = offsets[se[2 * t]] + sp[2 * t];
    int s1 = offsets[se[2 * t + 1]] + sp[2 * t + 1];
    float w0 = sw[2 * t], w1 = sw[2 * t + 1];
    float4 a = ((const float4*)(hout + (size_t)s0 * D_DIM))[tid];
    float4 b = ((const float4*)(hout + (size_t)s1 * D_DIM))[tid];
    float4 o;
    o.x = w0 * a.x + w1 * b.x; o.y = w0 * a.y + w1 * b.y;
    o.z = w0 * a.z + w1 * b.z; o.w = w0 * a.w + w1 * b.w;
    ((float4*)(out + (size_t)t * D_DIM))[tid] = o;
}

// ================= FALLBACK PATH (R1-proven, ~64.3MB ws) =================
#define BM 64
#define BN 64
#define LDSP 40

__global__ __launch_bounds__(256) void gemm1s_kernel(
    const float* __restrict__ x, const float* __restrict__ w1,
    const float* __restrict__ w3,
    const int* __restrict__ counts, const int* __restrict__ offsets,
    const int* __restrict__ tok, unsigned short* __restrict__ h)
{
    const int e = blockIdx.z;
    const int cnt = counts[e];
    const int tm = blockIdx.x;
    if (tm * BM >= cnt) return;
    const int tn = blockIdx.y;
    const int tid = threadIdx.x;

    __shared__ unsigned short As[BM][LDSP];
    __shared__ unsigned short B1s[BN][LDSP];
    __shared__ unsigned short B3s[BN][LDSP];
    __shared__ int tokS[BM];

    if (tid < BM) {
        int r = tm * BM + tid;
        tokS[tid] = (r < cnt) ? tok[e * MAXTOK + r] : -1;
    }
    __syncthreads();

    const int wave = tid >> 6;
    const int lane = tid & 63;
    const int wx = wave & 1, wy = wave >> 1;
    const int quad = lane >> 4, tl = lane & 15;

    floatx4 acc1[2][2], acc3[2][2];
#pragma unroll
    for (int a = 0; a < 2; a++)
#pragma unroll
        for (int b = 0; b < 2; b++) {
            acc1[a][b] = (floatx4){0.f, 0.f, 0.f, 0.f};
            acc3[a][b] = (floatx4){0.f, 0.f, 0.f, 0.f};
        }

    const float* w1e = w1 + (size_t)e * F_DIM * D_DIM + (size_t)(tn * BN) * D_DIM;
    const float* w3e = w3 + (size_t)e * F_DIM * D_DIM + (size_t)(tn * BN) * D_DIM;

    for (int kk = 0; kk < D_DIM; kk += 32) {
#pragma unroll
        for (int i = 0; i < 2; i++) {
            int j = tid + i * 256;
            int r = j >> 3, c4 = j & 7;
            float4 v = make_float4(0.f, 0.f, 0.f, 0.f);
            int tkn = tokS[r];
            if (tkn >= 0) v = *(const float4*)(x + (size_t)tkn * D_DIM + kk + c4 * 4);
            unsigned short* dst = &As[r][c4 * 4];
            dst[0] = f2bf(v.x); dst[1] = f2bf(v.y); dst[2] = f2bf(v.z); dst[3] = f2bf(v.w);
        }
#pragma unroll
        for (int i = 0; i < 2; i++) {
            int j = tid + i * 256;
            int r = j >> 3, c4 = j & 7;
            const float4 v1 = *(const float4*)(w1e + (size_t)r * D_DIM + kk + c4 * 4);
            const float4 v3 = *(const float4*)(w3e + (size_t)r * D_DIM + kk + c4 * 4);
            unsigned short* d1 = &B1s[r][c4 * 4];
            d1[0] = f2bf(v1.x); d1[1] = f2bf(v1.y); d1[2] = f2bf(v1.z); d1[3] = f2bf(v1.w);
            unsigned short* d3 = &B3s[r][c4 * 4];
            d3[0] = f2bf(v3.x); d3[1] = f2bf(v3.y); d3[2] = f2bf(v3.z); d3[3] = f2bf(v3.w);
        }
        __syncthreads();

        short8 a0 = *(const short8*)&As[wy * 32 + tl][quad * 8];
        short8 a1 = *(const short8*)&As[wy * 32 + 16 + tl][quad * 8];
        short8 b1a = *(const short8*)&B1s[wx * 32 + tl][quad * 8];
        short8 b1b = *(const short8*)&B1s[wx * 32 + 16 + tl][quad * 8];
        short8 b3a = *(const short8*)&B3s[wx * 32 + tl][quad * 8];
        short8 b3b = *(const short8*)&B3s[wx * 32 + 16 + tl][quad * 8];

        acc1[0][0] = __builtin_amdgcn_mfma_f32_16x16x32_bf16(a0, b1a, acc1[0][0], 0, 0, 0);
        acc1[0][1] = __builtin_amdgcn_mfma_f32_16x16x32_bf16(a0, b1b, acc1[0][1], 0, 0, 0);
        acc1[1][0] = __builtin_amdgcn_mfma_f32_16x16x32_bf16(a1, b1a, acc1[1][0], 0, 0, 0);
        acc1[1][1] = __builtin_amdgcn_mfma_f32_16x16x32_bf16(a1, b1b, acc1[1][1], 0, 0, 0);
        acc3[0][0] = __builtin_amdgcn_mfma_f32_16x16x32_bf16(a0, b3a, acc3[0][0], 0, 0, 0);
        acc3[0][1] = __builtin_amdgcn_mfma_f32_16x16x32_bf16(a0, b3b, acc3[0][1], 0, 0, 0);
        acc3[1][0] = __builtin_amdgcn_mfma_f32_16x16x32_bf16(a1, b3a, acc3[1][0], 0, 0, 0);
        acc3[1][1] = __builtin_amdgcn_mfma_f32_16x16x32_bf16(a1, b3b, acc3[1][1], 0, 0, 0);
        __syncthreads();
    }

    const int hbase = offsets[e];
#pragma unroll
    for (int mt = 0; mt < 2; mt++)
#pragma unroll
        for (int nt = 0; nt < 2; nt++)
#pragma unroll
            for (int i = 0; i < 4; i++) {
                int rl = wy * 32 + mt * 16 + quad * 4 + i;
                int r = tm * BM + rl;
                if (r < cnt) {
                    int c = tn * BN + wx * 32 + nt * 16 + tl;
                    float z1 = acc1[mt][nt][i];
                    float z3 = acc3[mt][nt][i];
                    float hv = (z1 / (1.f + expf(-z1))) * z3;
                    h[(size_t)(hbase + r) * F_DIM + c] = f2bf(hv);
                }
            }
}

__global__ __launch_bounds__(256) void gemm2s_kernel(
    const unsigned short* __restrict__ h, const float* __restrict__ w2,
    const int* __restrict__ counts, const int* __restrict__ offsets,
    const int* __restrict__ tok, const float* __restrict__ rw,
    float* __restrict__ out)
{
    const int e = blockIdx.z;
    const int cnt = counts[e];
    const int tm = blockIdx.x;
    if (tm * BM >= cnt) return;
    const int tn = blockIdx.y;
    const int tid = threadIdx.x;

    __shared__ unsigned short As[BM][LDSP];
    __shared__ unsigned short Bs[BN][LDSP];
    __shared__ int tokS[BM];
    __shared__ float rwS[BM];

    const int hbase = offsets[e];
    if (tid < BM) {
        int r = tm * BM + tid;
        tokS[tid] = (r < cnt) ? tok[e * MAXTOK + r] : -1;
        rwS[tid] = (r < cnt) ? rw[e * MAXTOK + r] : 0.f;
    }
    __syncthreads();

    const int wave = tid >> 6, lane = tid & 63;
    const int wx = wave & 1, wy = wave >> 1;
    const int quad = lane >> 4, tl = lane & 15;

    floatx4 acc[2][2];
#pragma unroll
    for (int a = 0; a < 2; a++)
#pragma unroll
        for (int b = 0; b < 2; b++) acc[a][b] = (floatx4){0.f, 0.f, 0.f, 0.f};

    const float* w2e = w2 + (size_t)e * D_DIM * F_DIM + (size_t)(tn * BN) * F_DIM;
    const unsigned short* hA = h + (size_t)(hbase + tm * BM) * F_DIM;

    for (int kk = 0; kk < F_DIM; kk += 32) {
        {
            int r = tid >> 2, c8 = tid & 3;
            short8 v = {0, 0, 0, 0, 0, 0, 0, 0};
            if (tm * BM + r < cnt) v = *(const short8*)(hA + (size_t)r * F_DIM + kk + c8 * 8);
            *(short8*)&As[r][c8 * 8] = v;
        }
#pragma unroll
        for (int i = 0; i < 2; i++) {
            int j = tid + i * 256;
            int r = j >> 3, c4 = j & 7;
            const float4 v = *(const float4*)(w2e + (size_t)r * F_DIM + kk + c4 * 4);
            unsigned short* dst = &Bs[r][c4 * 4];
            dst[0] = f2bf(v.x); dst[1] = f2bf(v.y); dst[2] = f2bf(v.z); dst[3] = f2bf(v.w);
        }
        __syncthreads();

        short8 a0 = *(const short8*)&As[wy * 32 + tl][quad * 8];
        short8 a1 = *(const short8*)&As[wy * 32 + 16 + tl][quad * 8];
        short8 b0 = *(const short8*)&Bs[wx * 32 + tl][quad * 8];
        short8 b1 = *(const short8*)&Bs[wx * 32 + 16 + tl][quad * 8];

        acc[0][0] = __builtin_amdgcn_mfma_f32_16x16x32_bf16(a0, b0, acc[0][0], 0, 0, 0);
        acc[0][1] = __builtin_amdgcn_mfma_f32_16x16x32_bf16(a0, b1, acc[0][1], 0, 0, 0);
        acc[1][0] = __builtin_amdgcn_mfma_f32_16x16x32_bf16(a1, b0, acc[1][0], 0, 0, 0);
        acc[1][1] = __builtin_amdgcn_mfma_f32_16x16x32_bf16(a1, b1, acc[1][1], 0, 0, 0);
        __syncthreads();
    }

#pragma unroll
    for (int mt = 0; mt < 2; mt++)
#pragma unroll
        for (int nt = 0; nt < 2; nt++)
#pragma unroll
            for (int i = 0; i < 4; i++) {
                int rl = wy * 32 + mt * 16 + quad * 4 + i;
                int r = tm * BM + rl;
                if (r < cnt) {
                    int t = tokS[rl];
                    float w = rwS[rl];
                    int c = tn * BN + wx * 32 + nt * 16 + tl;
                    atomicAdd(&out[(size_t)t * D_DIM + c], acc[mt][nt][i] * w);
                }
            }
}

// ================= launch =================
extern "C" void kernel_launch(void* const* d_in, const int* in_sizes, int n_in,
                              void* d_out, int out_size, void* d_ws, size_t ws_size,
                              hipStream_t stream)
{
    const float* x  = (const float*)d_in[0];
    const float* gw = (const float*)d_in[1];
    const float* w1 = (const float*)d_in[2];
    const float* w3 = (const float*)d_in[3];
    const float* w2 = (const float*)d_in[4];
    float* out = (float*)d_out;

    // common small region
    char* p = (char*)d_ws;
    int* counts  = (int*)p;            p += 64;
    int* offsets = (int*)p;            p += 64;
    int* tok     = (int*)p;            p += (size_t)E_NUM * MAXTOK * 4;   // 128KB
    float* rw    = (float*)p;          p += (size_t)E_NUM * MAXTOK * 4;   // 128KB

    // fast-path extra regions
    const size_t SEL = (size_t)2 * T_TOK * 4;              // 32KB each
    const size_t XB  = (size_t)T_TOK * D_DIM * 2;          // 8MiB
    const size_t WB  = (size_t)E_NUM * F_DIM * D_DIM * 2;  // 64MiB each
    const size_t HB  = (size_t)TOTROW * F_DIM * 2;         // 64MiB
    const size_t HO  = (size_t)TOTROW * D_DIM * 4;         // 32MiB
    const size_t small = (size_t)(p - (char*)d_ws);
    const size_t need_fast = small + 3 * SEL + XB + 3 * WB + HB + HO;

    if (ws_size >= need_fast) {
        int* se = (int*)p;               p += SEL;
        int* sp = (int*)p;               p += SEL;
        float* sw = (float*)p;           p += SEL;
        unsigned short* xb  = (unsigned short*)p;  p += XB;
        unsigned short* w1b = (unsigned short*)p;  p += WB;
        unsigned short* w3b = (unsigned short*)p;  p += WB;
        unsigned short* w2b = (unsigned short*)p;  p += WB;
        unsigned short* h   = (unsigned short*)p;  p += HB;
        float* hout = (float*)p;

        hipMemsetAsync(counts, 0, 64, stream);
        cvt_kernel<<<2048, 256, 0, stream>>>(x,  xb,  T_TOK * D_DIM / 8);
        cvt_kernel<<<8192, 256, 0, stream>>>(w1, w1b, E_NUM * F_DIM * D_DIM / 8);
        cvt_kernel<<<8192, 256, 0, stream>>>(w3, w3b, E_NUM * F_DIM * D_DIM / 8);
        cvt_kernel<<<8192, 256, 0, stream>>>(w2, w2b, E_NUM * F_DIM * D_DIM / 8);
        router_kernel<<<T_TOK, 64, 0, stream>>>(x, gw, counts, tok, rw, se, sp, sw);
        prefix_kernel<<<1, 64, 0, stream>>>(counts, offsets);
        dim3 g1(T_TOK / 128, F_DIM / 64, E_NUM);
        gemm1f_kernel<<<g1, 256, 0, stream>>>(xb, w1b, w3b, counts, offsets, tok, h);
        dim3 g2(T_TOK / 128, D_DIM / 128, E_NUM);
        gemm2f_kernel<<<g2, 256, 0, stream>>>(h, w2b, counts, offsets, hout);
        combine_kernel<<<T_TOK, 256, 0, stream>>>(hout, offsets, se, sp, sw, out);
    } else {
        // R1-proven fallback (~64.5MB ws)
        unsigned short* h = (unsigned short*)p;
        // router's se/sp/sw scribble into h region; gemm1s rewrites all of h afterwards
        int* se = (int*)h;
        int* sp = se + 2 * T_TOK;
        float* sw = (float*)(sp + 2 * T_TOK);

        hipMemsetAsync(counts, 0, 64, stream);
        hipMemsetAsync(d_out, 0, (size_t)out_size * sizeof(float), stream);
        router_kernel<<<T_TOK, 64, 0, stream>>>(x, gw, counts, tok, rw, se, sp, sw);
        prefix_kernel<<<1, 64, 0, stream>>>(counts, offsets);
        dim3 g1(T_TOK / BM, F_DIM / BN, E_NUM);
        gemm1s_kernel<<<g1, 256, 0, stream>>>(x, w1, w3, counts, offsets, tok, h);
        dim3 g2(T_TOK / BM, D_DIM / BN, E_NUM);
        gemm2s_kernel<<<g2, 256, 0, stream>>>(h, w2, counts, offsets, tok, rw, out);
    }
}